// Round 1
// baseline (856.706 us; speedup 1.0000x reference)
//
#include <hip/hip_runtime.h>
#include <hip/hip_bf16.h>
#include <stdint.h>

#define BATCH 8192
#define INSZ  1024
#define HID   2048
#define NTYPES 4
#define CH    32
#define KTOT  3072   // INSZ + HID
#define NTOT  4096   // ARITY * HID
#define EPSV  1e-5f

typedef __attribute__((ext_vector_type(8))) short short8;
typedef __attribute__((ext_vector_type(4))) float floatx4;

__device__ __forceinline__ uint16_t f2bf(float f) {
  __hip_bfloat16 h = __float2bfloat16(f);
  return *reinterpret_cast<uint16_t*>(&h);
}
__device__ __forceinline__ float bf2f(uint16_t s) {
  union { uint32_t u; float f; } c; c.u = ((uint32_t)s) << 16; return c.f;
}

// ---------- cast & concat: dst[r][0:1024]=s0[r][:], dst[r][1024:3072]=s1[r][:] ----------
__global__ __launch_bounds__(256) void cast_concat(
    const float* __restrict__ s0, const float* __restrict__ s1,
    uint16_t* __restrict__ dst, int tot4) {
  int i = blockIdx.x * 256 + threadIdx.x;
  if (i >= tot4) return;
  int r = i / (KTOT / 4);              // 768 groups of 4 per row
  int c = (i - r * (KTOT / 4)) * 4;    // element col, multiple of 4
  float4 v;
  if (c < INSZ) v = *(const float4*)(s0 + (int64_t)r * INSZ + c);
  else          v = *(const float4*)(s1 + (int64_t)r * HID + (c - INSZ));
  ushort4 o;
  o.x = f2bf(v.x); o.y = f2bf(v.y); o.z = f2bf(v.z); o.w = f2bf(v.w);
  *(ushort4*)(dst + (int64_t)i * 4) = o;
}

// ---------- GEMM: pre[M][N] = A[M][K] * W[N][K]^T + bias_ih[n] + bias_hh[n] ----------
#define BM 128
#define BN 128
#define BK 64

__global__ __launch_bounds__(256) void gemm_bt(
    const uint16_t* __restrict__ A,   // [BATCH][KTOT] bf16
    const uint16_t* __restrict__ W,   // [NTOT][KTOT]  bf16 (B^T layout)
    const float* __restrict__ bih, const float* __restrict__ bhh,
    uint16_t* __restrict__ pre)       // [BATCH][NTOT] bf16
{
  __shared__ uint16_t As[BM * BK];
  __shared__ uint16_t Bs[BN * BK];
  const int tid  = threadIdx.x;
  const int wave = tid >> 6;
  const int lane = tid & 63;
  const int wm = wave >> 1, wn = wave & 1;   // 2x2 waves, each 64x64 out
  const int row0 = blockIdx.y * BM;
  const int col0 = blockIdx.x * BN;

  floatx4 acc[4][4];
  #pragma unroll
  for (int m = 0; m < 4; ++m)
    #pragma unroll
    for (int n = 0; n < 4; ++n)
      acc[m][n] = (floatx4){0.f, 0.f, 0.f, 0.f};

  const int l8 = lane >> 3;          // 0..7  (row within 8-row chunk)
  const int c8 = (lane & 7) * 8;     // 0..56 (k element offset)

  for (int k0 = 0; k0 < KTOT; k0 += BK) {
    // stage A,B tiles: 16 chunks of 1KB each; wave w takes chunks i*4+w.
    // LDS dest is wave-uniform base; HW adds lane*16.
    #pragma unroll
    for (int i = 0; i < 4; ++i) {
      int chunk = i * 4 + wave;            // 0..15
      int rr = chunk * 8 + l8;             // tile row 0..127
      const uint16_t* ga = A + (int64_t)(row0 + rr) * KTOT + k0 + c8;
      __builtin_amdgcn_global_load_lds(
          (const __attribute__((address_space(1))) void*)ga,
          (__attribute__((address_space(3))) void*)(As + chunk * 512),
          16, 0, 0);
      const uint16_t* gb = W + (int64_t)(col0 + rr) * KTOT + k0 + c8;
      __builtin_amdgcn_global_load_lds(
          (const __attribute__((address_space(1))) void*)gb,
          (__attribute__((address_space(3))) void*)(Bs + chunk * 512),
          16, 0, 0);
    }
    __syncthreads();
    #pragma unroll
    for (int kt = 0; kt < BK; kt += 32) {
      short8 af[4], bfr[4];
      #pragma unroll
      for (int m = 0; m < 4; ++m)
        af[m] = *(const short8*)(As + (wm * 64 + m * 16 + (lane & 15)) * BK + kt + (lane >> 4) * 8);
      #pragma unroll
      for (int n = 0; n < 4; ++n)
        bfr[n] = *(const short8*)(Bs + (wn * 64 + n * 16 + (lane & 15)) * BK + kt + (lane >> 4) * 8);
      #pragma unroll
      for (int m = 0; m < 4; ++m)
        #pragma unroll
        for (int n = 0; n < 4; ++n)
          acc[m][n] = __builtin_amdgcn_mfma_f32_16x16x32_bf16(af[m], bfr[n], acc[m][n], 0, 0, 0);
    }
    __syncthreads();
  }

  // epilogue: C/D layout col=lane&15, row=(lane>>4)*4+j
  #pragma unroll
  for (int n = 0; n < 4; ++n) {
    int gc = col0 + wn * 64 + n * 16 + (lane & 15);
    float bias = bih[gc] + bhh[gc];
    #pragma unroll
    for (int m = 0; m < 4; ++m) {
      int gr0 = row0 + wm * 64 + m * 16 + ((lane >> 4) << 2);
      #pragma unroll
      for (int j = 0; j < 4; ++j) {
        pre[(int64_t)(gr0 + j) * NTOT + gc] = f2bf(acc[m][n][j] + bias);
      }
    }
  }
}

// ---------- LayerNorm + per-type 2->32->1 tanh MLP ----------
// one block (256 thr) per row; thread t: elements [16t,16t+16), neurons [8t,8t+8)
// type = t>>6 exactly (512 neurons per type, 8 per thread)
__global__ __launch_bounds__(256) void ln_mlp(
    const uint16_t* __restrict__ pre,
    const float* __restrict__ w1, const float* __restrict__ b1,
    const float* __restrict__ w2, const float* __restrict__ b2,
    float* __restrict__ out_all, float* __restrict__ out_xi)
{
  __shared__ float sW1[NTYPES * CH * 2];
  __shared__ float sB1[NTYPES * CH];
  __shared__ float sW2[NTYPES * CH];
  __shared__ float sB2[NTYPES];
  __shared__ float red[8];
  const int tid = threadIdx.x;
  for (int i = tid; i < NTYPES * CH * 2; i += 256) sW1[i] = w1[i];
  for (int i = tid; i < NTYPES * CH; i += 256) { sB1[i] = b1[i]; sW2[i] = w2[i]; }
  if (tid < NTYPES) sB2[tid] = b2[tid];

  const int row = blockIdx.x;
  const uint16_t* p = pre + (int64_t)row * NTOT + tid * 16;
  union { uint4 q[2]; uint16_t us[16]; } u;
  u.q[0] = *(const uint4*)(p);
  u.q[1] = *(const uint4*)(p + 8);
  float v[16];
  float s = 0.f, ss = 0.f;
  #pragma unroll
  for (int j = 0; j < 16; ++j) {
    v[j] = bf2f(u.us[j]);
    s += v[j];
    ss = fmaf(v[j], v[j], ss);
  }
  #pragma unroll
  for (int o = 32; o > 0; o >>= 1) {
    s  += __shfl_xor(s, o);
    ss += __shfl_xor(ss, o);
  }
  if ((tid & 63) == 0) { red[tid >> 6] = s; red[4 + (tid >> 6)] = ss; }
  __syncthreads();
  s  = red[0] + red[1] + red[2] + red[3];
  ss = red[4] + red[5] + red[6] + red[7];
  const float mu  = s * (1.f / NTOT);
  const float inv = rsqrtf(fmaf(-mu, mu, ss * (1.f / NTOT)) + EPSV);

  float lnv[16];
  #pragma unroll
  for (int j = 0; j < 16; ++j) lnv[j] = (v[j] - mu) * inv;

  float* xo = out_xi + (int64_t)row * NTOT + tid * 16;
  #pragma unroll
  for (int j = 0; j < 4; ++j)
    *(float4*)(xo + 4 * j) = make_float4(lnv[4*j], lnv[4*j+1], lnv[4*j+2], lnv[4*j+3]);

  const int type = tid >> 6;
  const float* W1 = sW1 + type * CH * 2;
  const float* B1 = sB1 + type * CH;
  const float* W2 = sW2 + type * CH;
  const float b2v = sB2[type];
  float ov[8];
  #pragma unroll
  for (int i = 0; i < 8; ++i) {
    const float x0 = lnv[2*i], x1 = lnv[2*i+1];
    float a = 0.f;
    #pragma unroll
    for (int c = 0; c < CH; ++c) {
      float z = fmaf(W1[2*c], x0, fmaf(W1[2*c+1], x1, B1[c]));
      float e = __expf(2.f * z);
      float h = 1.f - __fdividef(2.f, e + 1.f);   // tanh(z), NaN-safe at +-inf
      a = fmaf(h, W2[c], a);
    }
    ov[i] = a + b2v;
  }
  float* ao = out_all + (int64_t)row * HID + tid * 8;
  *(float4*)(ao)     = make_float4(ov[0], ov[1], ov[2], ov[3]);
  *(float4*)(ao + 4) = make_float4(ov[4], ov[5], ov[6], ov[7]);
}

extern "C" void kernel_launch(void* const* d_in, const int* in_sizes, int n_in,
                              void* d_out, int out_size, void* d_ws, size_t ws_size,
                              hipStream_t stream) {
  const float* x    = (const float*)d_in[0];
  const float* hx   = (const float*)d_in[1];
  const float* w_ih = (const float*)d_in[2];
  const float* w_hh = (const float*)d_in[3];
  const float* b_ih = (const float*)d_in[4];
  const float* b_hh = (const float*)d_in[5];
  const float* cw1  = (const float*)d_in[6];
  const float* cb1  = (const float*)d_in[7];
  const float* cw2  = (const float*)d_in[8];
  const float* cb2  = (const float*)d_in[9];

  float* out_all = (float*)d_out;                         // [8192*2048]
  float* out_xi  = out_all + (int64_t)BATCH * HID;        // [8192*4096]

  uint16_t* A_bf = (uint16_t*)d_ws;                       // 50.3 MB
  uint16_t* W_bf = A_bf + (int64_t)BATCH * KTOT;          // 25.2 MB
  uint16_t* pre  = W_bf + (int64_t)NTOT * KTOT;           // 67.1 MB

  {
    int tot4a = BATCH * (KTOT / 4);   // 6,291,456
    cast_concat<<<(tot4a + 255) / 256, 256, 0, stream>>>(x, hx, A_bf, tot4a);
    int tot4w = NTOT * (KTOT / 4);    // 3,145,728
    cast_concat<<<(tot4w + 255) / 256, 256, 0, stream>>>(w_ih, w_hh, W_bf, tot4w);
  }
  gemm_bt<<<dim3(NTOT / BN, BATCH / BM), 256, 0, stream>>>(A_bf, W_bf, b_ih, b_hh, pre);
  ln_mlp<<<BATCH, 256, 0, stream>>>(pre, cw1, cb1, cw2, cb2, out_all, out_xi);
}

// Round 2
// 683.210 us; speedup vs baseline: 1.2539x; 1.2539x over previous
//
#include <hip/hip_runtime.h>
#include <hip/hip_bf16.h>
#include <stdint.h>

#define BATCH 8192
#define INSZ  1024
#define HID   2048
#define NTYPES 4
#define CH    32
#define KTOT  3072   // INSZ + HID
#define NTOT  4096   // ARITY * HID
#define EPSV  1e-5f

typedef __attribute__((ext_vector_type(8))) short short8;
typedef __attribute__((ext_vector_type(4))) float floatx4;

__device__ __forceinline__ uint16_t f2bf(float f) {
  __hip_bfloat16 h = __float2bfloat16(f);
  return *reinterpret_cast<uint16_t*>(&h);
}
__device__ __forceinline__ float bf2f(uint16_t s) {
  union { uint32_t u; float f; } c; c.u = ((uint32_t)s) << 16; return c.f;
}

// ---------- cast & concat: dst[r][0:1024]=s0[r][:], dst[r][1024:3072]=s1[r][:] ----------
__global__ __launch_bounds__(256) void cast_concat(
    const float* __restrict__ s0, const float* __restrict__ s1,
    uint16_t* __restrict__ dst, int tot4) {
  int i = blockIdx.x * 256 + threadIdx.x;
  if (i >= tot4) return;
  int r = i / (KTOT / 4);              // 768 groups of 4 per row
  int c = (i - r * (KTOT / 4)) * 4;    // element col, multiple of 4
  float4 v;
  if (c < INSZ) v = *(const float4*)(s0 + (int64_t)r * INSZ + c);
  else          v = *(const float4*)(s1 + (int64_t)r * HID + (c - INSZ));
  ushort4 o;
  o.x = f2bf(v.x); o.y = f2bf(v.y); o.z = f2bf(v.z); o.w = f2bf(v.w);
  *(ushort4*)(dst + (int64_t)i * 4) = o;
}

// ---------- prep: merged, prescaled cell weights ----------
// mw[t*CH+c] = {K*w1[t][c][0], K*w1[t][c][1], K*b1[t][c], w2[t][c]},  K = 2*log2(e)
// w2s[t] = b2[t] + sum_c w2[t][c]
__global__ __launch_bounds__(128) void prep_weights(
    const float* __restrict__ w1, const float* __restrict__ b1,
    const float* __restrict__ w2, const float* __restrict__ b2,
    float4* __restrict__ mw, float* __restrict__ w2s) {
  const float Kc = 2.8853900817779268f;  // 2/ln(2)
  int t = threadIdx.x;           // 0..127
  int ty = t >> 5, c = t & 31;
  float a  = w1[(ty * CH + c) * 2 + 0];
  float bb = w1[(ty * CH + c) * 2 + 1];
  float b1v = b1[ty * CH + c];
  mw[ty * CH + c] = make_float4(Kc * a, Kc * bb, Kc * b1v, w2[ty * CH + c]);
  if (c == 0) {
    float s = b2[ty];
    for (int j = 0; j < CH; ++j) s += w2[ty * CH + j];
    w2s[ty] = s;
  }
}

// ---------- GEMM: pre[M][N] = A[M][K] * W[N][K]^T + bias_ih[n] + bias_hh[n] ----------
#define BM 128
#define BN 128
#define BK 64

__global__ __launch_bounds__(256) void gemm_bt(
    const uint16_t* __restrict__ A,   // [BATCH][KTOT] bf16
    const uint16_t* __restrict__ W,   // [NTOT][KTOT]  bf16 (B^T layout)
    const float* __restrict__ bih, const float* __restrict__ bhh,
    uint16_t* __restrict__ pre)       // [BATCH][NTOT] bf16
{
  __shared__ uint16_t As[BM * BK];
  __shared__ uint16_t Bs[BN * BK];
  const int tid  = threadIdx.x;
  const int wave = tid >> 6;
  const int lane = tid & 63;
  const int wm = wave >> 1, wn = wave & 1;   // 2x2 waves, each 64x64 out
  const int row0 = blockIdx.y * BM;
  const int col0 = blockIdx.x * BN;

  floatx4 acc[4][4];
  #pragma unroll
  for (int m = 0; m < 4; ++m)
    #pragma unroll
    for (int n = 0; n < 4; ++n)
      acc[m][n] = (floatx4){0.f, 0.f, 0.f, 0.f};

  const int l8 = lane >> 3;          // 0..7  (row within 8-row chunk)
  const int c8 = (lane & 7) * 8;     // 0..56 (k element offset)

  for (int k0 = 0; k0 < KTOT; k0 += BK) {
    #pragma unroll
    for (int i = 0; i < 4; ++i) {
      int chunk = i * 4 + wave;            // 0..15
      int rr = chunk * 8 + l8;             // tile row 0..127
      const uint16_t* ga = A + (int64_t)(row0 + rr) * KTOT + k0 + c8;
      __builtin_amdgcn_global_load_lds(
          (const __attribute__((address_space(1))) void*)ga,
          (__attribute__((address_space(3))) void*)(As + chunk * 512),
          16, 0, 0);
      const uint16_t* gb = W + (int64_t)(col0 + rr) * KTOT + k0 + c8;
      __builtin_amdgcn_global_load_lds(
          (const __attribute__((address_space(1))) void*)gb,
          (__attribute__((address_space(3))) void*)(Bs + chunk * 512),
          16, 0, 0);
    }
    __syncthreads();
    #pragma unroll
    for (int kt = 0; kt < BK; kt += 32) {
      short8 af[4], bfr[4];
      #pragma unroll
      for (int m = 0; m < 4; ++m)
        af[m] = *(const short8*)(As + (wm * 64 + m * 16 + (lane & 15)) * BK + kt + (lane >> 4) * 8);
      #pragma unroll
      for (int n = 0; n < 4; ++n)
        bfr[n] = *(const short8*)(Bs + (wn * 64 + n * 16 + (lane & 15)) * BK + kt + (lane >> 4) * 8);
      #pragma unroll
      for (int m = 0; m < 4; ++m)
        #pragma unroll
        for (int n = 0; n < 4; ++n)
          acc[m][n] = __builtin_amdgcn_mfma_f32_16x16x32_bf16(af[m], bfr[n], acc[m][n], 0, 0, 0);
    }
    __syncthreads();
  }

  // epilogue: C/D layout col=lane&15, row=(lane>>4)*4+j
  #pragma unroll
  for (int n = 0; n < 4; ++n) {
    int gc = col0 + wn * 64 + n * 16 + (lane & 15);
    float bias = bih[gc] + bhh[gc];
    #pragma unroll
    for (int m = 0; m < 4; ++m) {
      int gr0 = row0 + wm * 64 + m * 16 + ((lane >> 4) << 2);
      #pragma unroll
      for (int j = 0; j < 4; ++j) {
        pre[(int64_t)(gr0 + j) * NTOT + gc] = f2bf(acc[m][n][j] + bias);
      }
    }
  }
}

// ---------- LayerNorm + per-type 2->32->1 tanh MLP ----------
// one block (256 thr) per row; thread t: elements [16t,16t+16), neurons [8t,8t+8)
// type = t>>6 (wave-uniform). Weights via s_load from merged global table.
// tanh(z) = 1 - 2*rcp(exp2(K*z)+1); o = (b2+sum w2) - 2*sum w2c*rc
__global__ __launch_bounds__(256) void ln_mlp(
    const uint16_t* __restrict__ pre,
    const float4* __restrict__ mw,   // [NTYPES*CH] merged prescaled weights
    const float* __restrict__ w2s,   // [NTYPES]
    float* __restrict__ out_all, float* __restrict__ out_xi)
{
  __shared__ float red[8];
  const int tid = threadIdx.x;
  const int row = blockIdx.x;

  const uint16_t* p = pre + (int64_t)row * NTOT + tid * 16;
  union { uint4 q[2]; uint16_t us[16]; } u;
  u.q[0] = *(const uint4*)(p);
  u.q[1] = *(const uint4*)(p + 8);
  float v[16];
  float s = 0.f, ss = 0.f;
  #pragma unroll
  for (int j = 0; j < 16; ++j) {
    v[j] = bf2f(u.us[j]);
    s += v[j];
    ss = fmaf(v[j], v[j], ss);
  }
  #pragma unroll
  for (int o = 32; o > 0; o >>= 1) {
    s  += __shfl_xor(s, o);
    ss += __shfl_xor(ss, o);
  }
  if ((tid & 63) == 0) { red[tid >> 6] = s; red[4 + (tid >> 6)] = ss; }
  __syncthreads();
  s  = red[0] + red[1] + red[2] + red[3];
  ss = red[4] + red[5] + red[6] + red[7];
  const float mu  = s * (1.f / NTOT);
  const float inv = rsqrtf(fmaf(-mu, mu, ss * (1.f / NTOT)) + EPSV);

  float lnv[16];
  #pragma unroll
  for (int j = 0; j < 16; ++j) lnv[j] = (v[j] - mu) * inv;

  float* xo = out_xi + (int64_t)row * NTOT + tid * 16;
  #pragma unroll
  for (int j = 0; j < 4; ++j)
    *(float4*)(xo + 4 * j) = make_float4(lnv[4*j], lnv[4*j+1], lnv[4*j+2], lnv[4*j+3]);

  const int utype = __builtin_amdgcn_readfirstlane(tid >> 6);
  const float4* mwt = mw + utype * CH;
  const float w2sv = w2s[utype];

  float acc[8];
  #pragma unroll
  for (int i = 0; i < 8; ++i) acc[i] = 0.f;

  for (int c = 0; c < CH; ++c) {
    const float4 w = mwt[c];          // uniform -> s_load_dwordx4
    #pragma unroll
    for (int i = 0; i < 8; ++i) {
      float m = fmaf(w.x, lnv[2*i], fmaf(w.y, lnv[2*i+1], w.z));
      float e = __builtin_amdgcn_exp2f(m);          // exp2(K*z)
      float r = __builtin_amdgcn_rcpf(e + 1.f);     // 1/(e+1); inf-safe
      acc[i] = fmaf(w.w, r, acc[i]);
    }
  }

  float ov[8];
  #pragma unroll
  for (int i = 0; i < 8; ++i) ov[i] = fmaf(-2.f, acc[i], w2sv);

  float* ao = out_all + (int64_t)row * HID + tid * 8;
  *(float4*)(ao)     = make_float4(ov[0], ov[1], ov[2], ov[3]);
  *(float4*)(ao + 4) = make_float4(ov[4], ov[5], ov[6], ov[7]);
}

extern "C" void kernel_launch(void* const* d_in, const int* in_sizes, int n_in,
                              void* d_out, int out_size, void* d_ws, size_t ws_size,
                              hipStream_t stream) {
  const float* x    = (const float*)d_in[0];
  const float* hx   = (const float*)d_in[1];
  const float* w_ih = (const float*)d_in[2];
  const float* w_hh = (const float*)d_in[3];
  const float* b_ih = (const float*)d_in[4];
  const float* b_hh = (const float*)d_in[5];
  const float* cw1  = (const float*)d_in[6];
  const float* cb1  = (const float*)d_in[7];
  const float* cw2  = (const float*)d_in[8];
  const float* cb2  = (const float*)d_in[9];

  float* out_all = (float*)d_out;                         // [8192*2048]
  float* out_xi  = out_all + (int64_t)BATCH * HID;        // [8192*4096]

  uint16_t* A_bf = (uint16_t*)d_ws;                       // 50.3 MB
  uint16_t* W_bf = A_bf + (int64_t)BATCH * KTOT;          // 25.2 MB
  uint16_t* pre  = W_bf + (int64_t)NTOT * KTOT;           // 67.1 MB
  float4*   mw   = (float4*)(pre + (int64_t)BATCH * NTOT); // 2 KB
  float*    w2s  = (float*)(mw + NTYPES * CH);            // 16 B

  prep_weights<<<1, 128, 0, stream>>>(cw1, cb1, cw2, cb2, mw, w2s);
  {
    int tot4a = BATCH * (KTOT / 4);   // 6,291,456
    cast_concat<<<(tot4a + 255) / 256, 256, 0, stream>>>(x, hx, A_bf, tot4a);
    int tot4w = NTOT * (KTOT / 4);    // 3,145,728
    cast_concat<<<(tot4w + 255) / 256, 256, 0, stream>>>(w_ih, w_hh, W_bf, tot4w);
  }
  gemm_bt<<<dim3(NTOT / BN, BATCH / BM), 256, 0, stream>>>(A_bf, W_bf, b_ih, b_hh, pre);
  ln_mlp<<<BATCH, 256, 0, stream>>>(pre, mw, w2s, out_all, out_xi);
}